// Round 1
// baseline (493.519 us; speedup 1.0000x reference)
//
#include <hip/hip_runtime.h>
#include <stdint.h>

typedef unsigned int u32;
typedef unsigned short u16;
typedef __attribute__((ext_vector_type(8))) short bf16x8;
typedef __attribute__((ext_vector_type(16))) float f32x16;

#define DEVI __device__ __forceinline__

// ---------------- numeric helpers ----------------
DEVI u16 f2b_rne(float f) {
  u32 u = __float_as_uint(f);
  u += 0x7FFFu + ((u >> 16) & 1u);
  return (u16)(u >> 16);
}
// pack high 16 bits of two f32 bit-patterns: [bf16(hi)][bf16(lo)] (truncate)
DEVI u32 pack_hi16(u32 hi, u32 lo) {
  return __builtin_amdgcn_perm(hi, lo, 0x07060302u);
}
DEVI u32 mul2bf(u32 a, u32 b) {  // two bf16 lanes: product, repacked bf16
  float a0 = __uint_as_float(a << 16);
  float a1 = __uint_as_float(a & 0xFFFF0000u);
  float b0 = __uint_as_float(b << 16);
  float b1 = __uint_as_float(b & 0xFFFF0000u);
  return pack_hi16(__float_as_uint(a1 * b1), __float_as_uint(a0 * b0));
}
DEVI u32 absdiff2bf(u32 a, u32 b) {  // two bf16 lanes: |a-b|, repacked bf16
  float a0 = __uint_as_float(a << 16);
  float a1 = __uint_as_float(a & 0xFFFF0000u);
  float b0 = __uint_as_float(b << 16);
  float b1 = __uint_as_float(b & 0xFFFF0000u);
  return pack_hi16(__float_as_uint(fabsf(a1 - b1)), __float_as_uint(fabsf(a0 - b0)));
}

// ---------------- ws layout (bytes) ----------------
// E16  : [0, 1MB)      bf16 embeddings, [1024 rows][512]
// W16T : [1MB, 3MB)    bf16 W1 transposed, [512 ch][2048 k]
// a    : [3MB, 5MB)    f32 e@Wa, [1024 rows][512]
// c    : [5MB, 7MB)    f32 e@Wb, [1024 rows][512]
#define WS_E16 0
#define WS_WT (1u << 20)
#define WS_A (3u << 20)
#define WS_C (5u << 20)

// ---------------- kernel 0a: E -> bf16 ----------------
__global__ void k_cvt_e(const float* __restrict__ E, u16* __restrict__ E16) {
  int i = (blockIdx.x * blockDim.x + threadIdx.x) * 4;  // 524288 total, exact
  float4 v = *(const float4*)(E + i);
  ushort4 o;
  o.x = f2b_rne(v.x); o.y = f2b_rne(v.y); o.z = f2b_rne(v.z); o.w = f2b_rne(v.w);
  *(ushort4*)(E16 + i) = o;
}

// ---------------- kernel 0b: W1 (2048x512 f32) -> W16T (512x2048 bf16) ----------------
__global__ void k_cvt_w(const float* __restrict__ W1, u16* __restrict__ WT) {
  __shared__ float tile[64][65];
  int t = threadIdx.x;
  int kBase = blockIdx.x * 64;   // 32 tiles
  int chBase = blockIdx.y * 64;  // 8 tiles
  int lr = t >> 4, lc = (t & 15) * 4;
  for (int rr = 0; rr < 4; rr++) {
    int kr = lr + rr * 16;
    float4 v = *(const float4*)(W1 + (kBase + kr) * 512 + chBase + lc);
    tile[kr][lc] = v.x; tile[kr][lc + 1] = v.y;
    tile[kr][lc + 2] = v.z; tile[kr][lc + 3] = v.w;
  }
  __syncthreads();
  int ch = t >> 2, ks = (t & 3) * 16;
  u32 w[8];
  for (int u = 0; u < 8; u++) {
    u16 lo = f2b_rne(tile[ks + 2 * u][ch]);
    u16 hi = f2b_rne(tile[ks + 2 * u + 1][ch]);
    w[u] = (u32)lo | ((u32)hi << 16);
  }
  u16* dst = WT + (chBase + ch) * 2048 + kBase + ks;
  uint4 s0; s0.x = w[0]; s0.y = w[1]; s0.z = w[2]; s0.w = w[3];
  uint4 s1; s1.x = w[4]; s1.y = w[5]; s1.z = w[6]; s1.w = w[7];
  *(uint4*)(dst) = s0;
  *(uint4*)(dst + 8) = s1;
}

// ---------------- kernel 1: a = E@Wa, c = E@Wb (bf16 MFMA, f32 out) ----------------
// M=1024 rows, N'=1024 (a||c), K=512. 128x128 block tile, 4 waves 2x2, wave 64x64.
__global__ __launch_bounds__(256, 4) void k_ac(const u16* __restrict__ E16,
                                               const u16* __restrict__ WT,
                                               float* __restrict__ Aw,
                                               float* __restrict__ Cw) {
  __shared__ __align__(16) char smem[16384];
  char* sA = smem;         // [128 rows][32 k] bf16, 16B-group xor swizzle
  char* sB = smem + 8192;  // [128 ch][32 k] bf16
  const int tid = threadIdx.x;
  const int lane = tid & 63, wid = tid >> 6;
  const int wr = wid >> 1, wcl = wid & 1;
  const int n = lane & 31, q = lane >> 5;
  const int rowBase = blockIdx.y * 128;
  const int chBase = blockIdx.x * 128;
  const int halfOff = (chBase >= 512) ? 512 : 0;  // a-half vs c-half of W1
  const int chSrc0 = chBase - halfOff;
  f32x16 acc[2][2];
  for (int a = 0; a < 2; a++)
    for (int c = 0; c < 2; c++)
      for (int e = 0; e < 16; e++) acc[a][c][e] = 0.f;
  for (int kc = 0; kc < 16; kc++) {
    const int k0 = kc * 32;
    __syncthreads();
    for (int s2 = 0; s2 < 2; s2++) {
      int s = tid * 2 + s2;
      int row = s >> 2, pg = s & 3, lg = pg ^ (row & 3);
      *(uint4*)(sA + row * 64 + pg * 16) =
          *(const uint4*)(E16 + (rowBase + row) * 512 + k0 + lg * 8);
      *(uint4*)(sB + row * 64 + pg * 16) =
          *(const uint4*)(WT + (chSrc0 + row) * 2048 + halfOff + k0 + lg * 8);
    }
    __syncthreads();
    for (int ks = 0; ks < 2; ks++) {
      int kg = ks * 2 + q;
      bf16x8 af[2], bfr[2];
      for (int rb = 0; rb < 2; rb++) {
        int row = wr * 64 + rb * 32 + n;
        af[rb] = *(const bf16x8*)(sA + row * 64 + ((kg ^ (n & 3)) * 16));
      }
      for (int cb = 0; cb < 2; cb++) {
        int ch = wcl * 64 + cb * 32 + n;
        bfr[cb] = *(const bf16x8*)(sB + ch * 64 + ((kg ^ (n & 3)) * 16));
      }
      for (int rb = 0; rb < 2; rb++)
        for (int cb = 0; cb < 2; cb++)
          acc[rb][cb] = __builtin_amdgcn_mfma_f32_32x32x16_bf16(af[rb], bfr[cb],
                                                               acc[rb][cb], 0, 0, 0);
    }
  }
  for (int rb = 0; rb < 2; rb++)
    for (int cb = 0; cb < 2; cb++)
      for (int r = 0; r < 16; r++) {
        int rowl = (r & 3) + 8 * (r >> 2) + 4 * q;  // C/D layout (m74/m101)
        int rowg = rowBase + wr * 64 + rb * 32 + rowl;
        int chg = chBase + wcl * 64 + cb * 32 + n;
        float v = acc[rb][cb][r];
        if (chg < 512) Aw[rowg * 512 + chg] = v;
        else Cw[rowg * 512 + chg - 512] = v;
      }
}

// ---------------- kernel 2: pair kernel ----------------
// Block: 8 i x 16 j = 128 pairs, 256 thr (4 waves, 2x2), 2 channel passes of 256,
// K=1024 ([u;v] vs W1 rows 1024..2047) in chunks of 32. Wave tile 64 pairs x 128 ch.
#define ESTR 520  // e-row stride in LDS (elems): breaks bank alignment, keeps 16B align
#define EI_OFF 0             // 8*520*2   = 8320
#define EJ_OFF 8320          // 16*520*2  = 16640 -> 24960
#define A2_OFF 24960         // 128*32*2  = 8192  -> 33152
#define B2_OFF 33152         // 256*32*2  = 16384 -> 49536
#define CJB_OFF 24960        // epilogue alias: 16*256*4 = 16384
#define W2S_OFF 41344        // 256*4 = 1024
#define RED_OFF 49536        // [128][9] f32 = 4608
#define SMEM2 54144

__global__ __launch_bounds__(256, 2) void k_pair(
    const u16* __restrict__ E16, const u16* __restrict__ WT,
    const float* __restrict__ Aw, const float* __restrict__ Cw,
    const float* __restrict__ b1, const float* __restrict__ w2,
    const float* __restrict__ b2, float* __restrict__ out) {
  __shared__ __align__(16) char smem[SMEM2];
  const int tid = threadIdx.x;
  const int lane = tid & 63, wid = tid >> 6;
  const int wr = wid >> 1, wcl = wid & 1;
  const int n = lane & 31, q = lane >> 5;
  const int bb = blockIdx.z;
  const int bi0 = blockIdx.y * 8;
  const int bj0 = blockIdx.x * 16;

  // stage e-tiles into LDS (rows 0..7 = e_i tile, 8..23 = e_j tile)
  for (int s = tid; s < 1536; s += 256) {
    int row = s >> 6, c16 = s & 63;
    int grow = (row < 8) ? (bi0 + row) : (bj0 + row - 8);
    const u16* src = E16 + (bb * 256 + grow) * 512 + c16 * 8;
    int off = (row < 8) ? (EI_OFF + (row * ESTR + c16 * 8) * 2)
                        : (EJ_OFF + ((row - 8) * ESTR + c16 * 8) * 2);
    *(uint4*)(smem + off) = *(const uint4*)src;
  }

  float* RED = (float*)(smem + RED_OFF);

  for (int pass = 0; pass < 2; pass++) {
    const int ch0 = pass * 256;
    f32x16 acc[2][4];
    for (int a = 0; a < 2; a++)
      for (int c = 0; c < 4; c++)
        for (int e = 0; e < 16; e++) acc[a][c][e] = 0.f;

    for (int kc = 0; kc < 32; kc++) {
      const int k0 = kc * 32;
      const int dB = k0 & 511;       // source d within e-rows
      const bool isV = (k0 >= 512);  // u-part (e_i*e_j) vs v-part |e_i-e_j|
      __syncthreads();
      // stage B chunk [256 ch][32 k] bf16 from W16T rows, cols 1024+k0..
      for (int s2 = 0; s2 < 4; s2++) {
        int s = tid + 256 * s2;
        int row = s >> 2, pg = s & 3, lg = pg ^ (row & 3);
        *(uint4*)(smem + B2_OFF + row * 64 + pg * 16) =
            *(const uint4*)(WT + (ch0 + row) * 2048 + 1024 + k0 + lg * 8);
      }
      // form A chunk [128 pairs][32 k]
      {
        int p = tid >> 1;
        int iL = p >> 4, jL = p & 15;
        const char* ei = smem + EI_OFF + iL * (ESTR * 2);
        const char* ej = smem + EJ_OFF + jL * (ESTR * 2);
        for (int s2 = 0; s2 < 2; s2++) {
          int kg = 2 * (tid & 1) + s2;
          int d0 = dB + kg * 8;
          uint4 va = *(const uint4*)(ei + d0 * 2);
          uint4 vb = *(const uint4*)(ej + d0 * 2);
          uint4 o;
          if (!isV) {
            o.x = mul2bf(va.x, vb.x); o.y = mul2bf(va.y, vb.y);
            o.z = mul2bf(va.z, vb.z); o.w = mul2bf(va.w, vb.w);
          } else {
            o.x = absdiff2bf(va.x, vb.x); o.y = absdiff2bf(va.y, vb.y);
            o.z = absdiff2bf(va.z, vb.z); o.w = absdiff2bf(va.w, vb.w);
          }
          *(uint4*)(smem + A2_OFF + p * 64 + ((kg ^ (p & 3)) * 16)) = o;
        }
      }
      __syncthreads();
      // MFMA: 2 ksteps x (2 row-blocks x 4 ch-blocks)
      for (int ks = 0; ks < 2; ks++) {
        int kg = ks * 2 + q;
        bf16x8 af[2], bfr[4];
        for (int rb = 0; rb < 2; rb++) {
          int row = wr * 64 + rb * 32 + n;
          af[rb] = *(const bf16x8*)(smem + A2_OFF + row * 64 + ((kg ^ (n & 3)) * 16));
        }
        for (int cb = 0; cb < 4; cb++) {
          int ch = wcl * 128 + cb * 32 + n;
          bfr[cb] = *(const bf16x8*)(smem + B2_OFF + ch * 64 + ((kg ^ (n & 3)) * 16));
        }
        for (int rb = 0; rb < 2; rb++)
          for (int cb = 0; cb < 4; cb++)
            acc[rb][cb] = __builtin_amdgcn_mfma_f32_32x32x16_bf16(af[rb], bfr[cb],
                                                                 acc[rb][cb], 0, 0, 0);
      }
    }

    // ---- epilogue for this pass ----
    __syncthreads();
    {
      float b1v = b1[ch0 + tid];
      for (int j = 0; j < 16; j++)
        *(float*)(smem + CJB_OFF + (j * 256 + tid) * 4) =
            Cw[(bb * 256 + bj0 + j) * 512 + ch0 + tid] + b1v;
      *(float*)(smem + W2S_OFF + tid * 4) = w2[ch0 + tid];
    }
    __syncthreads();

    const float* CJB = (const float*)(smem + CJB_OFF);
    const float* W2S = (const float*)(smem + W2S_OFF);
    for (int rb = 0; rb < 2; rb++) {
      float av[4][2], w2v[4];
      int chls[4];
      for (int cb = 0; cb < 4; cb++) {
        int chl = wcl * 128 + cb * 32 + n;
        chls[cb] = chl;
        w2v[cb] = W2S[chl];
        int irow = bb * 256 + bi0 + wr * 4 + rb * 2;
        av[cb][0] = Aw[irow * 512 + ch0 + chl];
        av[cb][1] = Aw[(irow + 1) * 512 + ch0 + chl];
      }
      for (int r = 0; r < 16; r++) {
        int rowl = (r & 3) + 8 * (r >> 2) + 4 * q;  // C/D layout
        int j = rowl & 15;
        int hi = r >> 3;
        float v = 0.f;
        for (int cb = 0; cb < 4; cb++) {
          float h = acc[rb][cb][r] + av[cb][hi] + CJB[j * 256 + chls[cb]];
          if (h > 0.f) v += h * w2v[cb];
        }
        v += __shfl_xor(v, 1);
        v += __shfl_xor(v, 2);
        v += __shfl_xor(v, 4);
        if ((n & 7) == 0) {
          int p = wr * 64 + rb * 32 + rowl;
          int slot = p * 9 + wcl * 4 + (n >> 3);
          if (pass == 0) RED[slot] = v;
          else RED[slot] += v;
        }
      }
    }
  }

  __syncthreads();
  if (tid < 128) {
    float s = b2[0];
    for (int u = 0; u < 8; u++) s += RED[tid * 9 + u];
    out[(bb * 256 + bi0 + (tid >> 4)) * 256 + bj0 + (tid & 15)] = s;
  }
}

// ---------------- launcher ----------------
extern "C" void kernel_launch(void* const* d_in, const int* in_sizes, int n_in,
                              void* d_out, int out_size, void* d_ws, size_t ws_size,
                              hipStream_t stream) {
  const float* E = (const float*)d_in[0];
  const float* W1 = (const float*)d_in[1];
  const float* b1 = (const float*)d_in[2];
  const float* W2 = (const float*)d_in[3];
  const float* b2 = (const float*)d_in[4];
  float* out = (float*)d_out;
  char* ws = (char*)d_ws;
  u16* E16 = (u16*)(ws + WS_E16);
  u16* WT = (u16*)(ws + WS_WT);
  float* Aw = (float*)(ws + WS_A);
  float* Cw = (float*)(ws + WS_C);

  hipLaunchKernelGGL(k_cvt_e, dim3(512), dim3(256), 0, stream, E, E16);
  hipLaunchKernelGGL(k_cvt_w, dim3(32, 8), dim3(256), 0, stream, W1, WT);
  hipLaunchKernelGGL(k_ac, dim3(8, 8), dim3(256), 0, stream, E16, WT, Aw, Cw);
  hipLaunchKernelGGL(k_pair, dim3(16, 32, 4), dim3(256), 0, stream,
                     E16, WT, Aw, Cw, b1, W2, b2, out);
}